// Round 1
// baseline (7040.615 us; speedup 1.0000x reference)
//
#include <hip/hip_runtime.h>
#include <hip/hip_bf16.h>

typedef unsigned short u16;
typedef __bf16 bf16x8 __attribute__((ext_vector_type(8)));
typedef float f32x4 __attribute__((ext_vector_type(4)));

// ---------------- constants ----------------
#define BATCH 32
#define NTOK 197       // 196 patches + cls
#define DIM 768
#define LAYERS 12
#define HEADS 12
#define DHEAD 64
#define MLPD 3072
#define NCLS 1000
#define SROWS 6304     // BATCH*NTOK
#define SLD 208        // padded attention row stride

// workspace offsets (bytes), all 256-aligned
constexpr long OFF_X  = 0;                      // fp32 residual [6304,768]
constexpr long OFF_H  = 19365888;               // bf16 LN out  [6304,768]
constexpr long OFF_O  = 29048832;               // bf16 attn out [6304,768]
constexpr long OFF_WB = 38731776;               // bf16 weight scratch [3072*768]
constexpr long OFF_Q  = 43450368;               // bf16 q [384,197,64]  (also patchA / mlp_h)
constexpr long OFF_K  = 53133312;               // bf16 k [384,197,64]
constexpr long OFF_VT = 62816256;               // bf16 v^T [384,64,208]
constexpr long OFF_S  = 73039872;               // bf16 S [384,197,208]
constexpr long OFF_PL = 104509440;              // fp32 pooled [32,768]
constexpr long OFF_HB = 104607744;              // bf16 head LN out [32,768]

// ---------------- helpers ----------------
__device__ inline u16 f2bf(float f) {
    __hip_bfloat16 h = __float2bfloat16(f);
    return __builtin_bit_cast(u16, h);
}
__device__ inline float bf2f(u16 u) {
    unsigned int x = ((unsigned int)u) << 16;
    return __builtin_bit_cast(float, x);
}

// ---------------- small kernels ----------------
__global__ __launch_bounds__(256) void im2col_kernel(
        const float* __restrict__ imgs, u16* __restrict__ out) {
    int idx = blockIdx.x * 256 + threadIdx.x;          // 6272*768
    if (idx >= 6272 * 768) return;
    int col = idx % 768, row = idx / 768;
    int b = row / 196, p = row % 196;
    int py = p / 14, px = p % 14;
    int c = col >> 8, ph = (col >> 4) & 15, pw = col & 15;
    float v = imgs[(((long)b * 3 + c) * 224 + (py * 16 + ph)) * 224 + (px * 16 + pw)];
    out[idx] = f2bf(v);
}

__global__ __launch_bounds__(256) void cast_kernel(
        const float* __restrict__ in, u16* __restrict__ out, int n) {
    int idx = blockIdx.x * 256 + threadIdx.x;
    if (idx < n) out[idx] = f2bf(in[idx]);
}

__global__ __launch_bounds__(256) void transpose_cast(
        const float* __restrict__ in, u16* __restrict__ out, int R, int C) {
    __shared__ float tile[32][33];
    int bx = blockIdx.x * 32;   // col base
    int by = blockIdx.y * 32;   // row base
    int tx = threadIdx.x & 31, ty = threadIdx.x >> 5;
#pragma unroll
    for (int i = 0; i < 32; i += 8) {
        int r = by + ty + i, c = bx + tx;
        if (r < R && c < C) tile[ty + i][tx] = in[(long)r * C + c];
    }
    __syncthreads();
#pragma unroll
    for (int i = 0; i < 32; i += 8) {
        int c = bx + ty + i, r = by + tx;
        if (r < R && c < C) out[(long)c * R + r] = f2bf(tile[tx][ty + i]);
    }
}

__global__ __launch_bounds__(256) void add_pos_kernel(
        float* __restrict__ x, const float* __restrict__ cls,
        const float* __restrict__ pos) {
    int idx = blockIdx.x * 256 + threadIdx.x;          // 6304*768
    if (idx >= SROWS * DIM) return;
    int d = idx % DIM, row = idx / DIM, n = row % NTOK;
    if (n == 0) x[idx] = cls[d] + pos[d];
    else        x[idx] += pos[(long)n * DIM + d];
}

__device__ inline float block_sum(float v, float* red) {
#pragma unroll
    for (int off = 32; off; off >>= 1) v += __shfl_xor(v, off, 64);
    int w = threadIdx.x >> 6;
    if ((threadIdx.x & 63) == 0) red[w] = v;
    __syncthreads();
    float s = red[0] + red[1] + red[2] + red[3];
    __syncthreads();
    return s;
}

__global__ __launch_bounds__(256) void ln_kernel(
        const float* __restrict__ x, const float* __restrict__ g,
        const float* __restrict__ bt, u16* __restrict__ out) {
    __shared__ float red[4];
    long row = blockIdx.x;
    const float* xr = x + row * DIM;
    int t = threadIdx.x;
    float v0 = xr[t], v1 = xr[t + 256], v2 = xr[t + 512];
    float mean = block_sum(v0 + v1 + v2, red) * (1.f / 768.f);
    float d0 = v0 - mean, d1 = v1 - mean, d2 = v2 - mean;
    float var = block_sum(d0 * d0 + d1 * d1 + d2 * d2, red) * (1.f / 768.f);
    float rs = rsqrtf(var + 1e-5f);
    u16* o = out + row * DIM;
    o[t]       = f2bf(d0 * rs * g[t]       + bt[t]);
    o[t + 256] = f2bf(d1 * rs * g[t + 256] + bt[t + 256]);
    o[t + 512] = f2bf(d2 * rs * g[t + 512] + bt[t + 512]);
}

__global__ __launch_bounds__(256) void softmax_rows(u16* __restrict__ S) {
    int row = blockIdx.x * 4 + (threadIdx.x >> 6);      // 384*197 rows exactly
    int lane = threadIdx.x & 63;
    u16* p = S + (long)row * SLD;
    float v[4];
#pragma unroll
    for (int i = 0; i < 4; i++) {
        int c = lane + i * 64;
        v[i] = (c < NTOK) ? bf2f(p[c]) : -1e30f;
    }
    float mx = fmaxf(fmaxf(v[0], v[1]), fmaxf(v[2], v[3]));
#pragma unroll
    for (int off = 32; off; off >>= 1) mx = fmaxf(mx, __shfl_xor(mx, off, 64));
    float s = 0.f;
#pragma unroll
    for (int i = 0; i < 4; i++) {
        v[i] = (v[i] > -1e29f) ? __expf(v[i] - mx) : 0.f;
        s += v[i];
    }
#pragma unroll
    for (int off = 32; off; off >>= 1) s += __shfl_xor(s, off, 64);
    float inv = 1.f / s;
#pragma unroll
    for (int i = 0; i < 4; i++) {
        int c = lane + i * 64;
        if (c < NTOK) p[c] = f2bf(v[i] * inv);
    }
}

__global__ __launch_bounds__(256) void mean_pool_kernel(
        const float* __restrict__ x, float* __restrict__ pooled) {
    int idx = blockIdx.x * 256 + threadIdx.x;          // 32*768
    if (idx >= BATCH * DIM) return;
    int b = idx / DIM, d = idx % DIM;
    float s = 0.f;
    for (int n = 0; n < NTOK; n++) s += x[((long)b * NTOK + n) * DIM + d];
    pooled[idx] = s * (1.f / 197.f);
}

__global__ __launch_bounds__(256) void head_kernel(
        const u16* __restrict__ hx, const float* __restrict__ hw,
        const float* __restrict__ hb, float* __restrict__ out) {
    __shared__ float xr[DIM];
    int b = blockIdx.x;
    for (int i = threadIdx.x; i < DIM; i += 256) xr[i] = bf2f(hx[b * DIM + i]);
    __syncthreads();
    for (int c = threadIdx.x; c < NCLS; c += 256) {
        float s = hb[c];
        for (int d = 0; d < DIM; d++) s += xr[d] * hw[(long)d * NCLS + c];
        out[b * NCLS + c] = s;
    }
}

// ---------------- MFMA GEMM ----------------
// C[M,N] = A[M,K](bf16, row-major, lda) * B^T  with B stored [N,K](bf16, ldb)
// 128x128 tile, BK=32, 4 waves each 64x64 (4x4 MFMA 16x16x32), LDS rows padded to 40 bf16.
constexpr int OM_F32 = 0, OM_BF16 = 1, OM_PATCH = 2, OM_QK = 3, OM_VT = 4,
              OM_S = 5, OM_ATTN = 6;
constexpr int EPI_NONE = 0, EPI_GELU = 1;

template<int OUT_MODE, int EPI, bool RESID>
__global__ __launch_bounds__(256, 2) void gemm_tile(
        const u16* __restrict__ Aall, const u16* __restrict__ Ball,
        void* __restrict__ Cptr, const float* __restrict__ bias,
        int M, int N, int K, int lda, int ldb, int ldc,
        long sA, long sB, float scale) {
    __shared__ int4 As4[128 * 5];
    __shared__ int4 Bs4[128 * 5];
    int g = blockIdx.z;
    const u16* A = Aall + (long)g * sA;
    const u16* B = Ball + (long)g * sB;
    int m0 = blockIdx.x * 128;
    int n0 = blockIdx.y * 128;
    int tid = threadIdx.x;
    int lane = tid & 63;
    int wave = tid >> 6;
    int wm = (wave & 1) * 64;
    int wn = (wave >> 1) * 64;
    int lm = lane & 15;
    int lq = lane >> 4;

    f32x4 acc[4][4];
    const f32x4 z4 = {0.f, 0.f, 0.f, 0.f};
#pragma unroll
    for (int i = 0; i < 4; i++)
#pragma unroll
        for (int j = 0; j < 4; j++) acc[i][j] = z4;

    int r_loc = tid >> 2;            // 0..63
    int kc = (tid & 3) * 8;          // 0,8,16,24

    for (int k0 = 0; k0 < K; k0 += 32) {
#pragma unroll
        for (int half = 0; half < 2; ++half) {
            int rr = r_loc + half * 64;
            int gk = k0 + kc;
            {   // stage A
                int gr = m0 + rr;
                int4 val;
                if (gr < M && gk + 8 <= K) {
                    val = *reinterpret_cast<const int4*>(A + (long)gr * lda + gk);
                } else {
                    alignas(16) u16 tmp[8];
#pragma unroll
                    for (int j = 0; j < 8; j++)
                        tmp[j] = (gr < M && gk + j < K) ? A[(long)gr * lda + gk + j] : (u16)0;
                    val = *reinterpret_cast<int4*>(tmp);
                }
                As4[rr * 5 + (kc >> 3)] = val;
            }
            {   // stage B (stored [N,K])
                int gr = n0 + rr;
                int4 val;
                if (gr < N && gk + 8 <= K) {
                    val = *reinterpret_cast<const int4*>(B + (long)gr * ldb + gk);
                } else {
                    alignas(16) u16 tmp[8];
#pragma unroll
                    for (int j = 0; j < 8; j++)
                        tmp[j] = (gr < N && gk + j < K) ? B[(long)gr * ldb + gk + j] : (u16)0;
                    val = *reinterpret_cast<int4*>(tmp);
                }
                Bs4[rr * 5 + (kc >> 3)] = val;
            }
        }
        __syncthreads();
        bf16x8 af[4], bfr[4];
#pragma unroll
        for (int i = 0; i < 4; i++)
            af[i] = __builtin_bit_cast(bf16x8, As4[(wm + i * 16 + lm) * 5 + lq]);
#pragma unroll
        for (int i = 0; i < 4; i++)
            bfr[i] = __builtin_bit_cast(bf16x8, Bs4[(wn + i * 16 + lm) * 5 + lq]);
#pragma unroll
        for (int mi = 0; mi < 4; mi++)
#pragma unroll
            for (int ni = 0; ni < 4; ni++)
                acc[mi][ni] = __builtin_amdgcn_mfma_f32_16x16x32_bf16(
                        af[mi], bfr[ni], acc[mi][ni], 0, 0, 0);
        __syncthreads();
    }

    // epilogue: C/D layout col=lane&15, row=(lane>>4)*4+reg
#pragma unroll
    for (int mi = 0; mi < 4; mi++) {
#pragma unroll
        for (int ni = 0; ni < 4; ni++) {
#pragma unroll
            for (int r = 0; r < 4; r++) {
                int m = m0 + wm + mi * 16 + lq * 4 + r;
                int n = n0 + wn + ni * 16 + lm;
                if (m < M && n < N) {
                    float v = acc[mi][ni][r] * scale;
                    if (bias) v += bias[n];
                    if (EPI == EPI_GELU) {
                        float u = v;
                        v = 0.5f * u * (1.f + tanhf(0.7978845608028654f *
                                                    (u + 0.044715f * u * u * u)));
                    }
                    if (OUT_MODE == OM_F32) {
                        float* Cf = (float*)Cptr;
                        long idx = (long)m * ldc + n;
                        if (RESID) v += Cf[idx];
                        Cf[idx] = v;
                    } else if (OUT_MODE == OM_BF16) {
                        ((u16*)Cptr)[(long)m * ldc + n] = f2bf(v);
                    } else if (OUT_MODE == OM_PATCH) {
                        int row = m + m / 196 + 1;   // skip cls row of each batch
                        ((float*)Cptr)[(long)row * DIM + n] = v;
                    } else if (OUT_MODE == OM_QK) {
                        int b = m / NTOK, tok = m - b * NTOK;
                        int h = n >> 6, dh = n & 63;
                        ((u16*)Cptr)[((((long)b * HEADS + h) * NTOK + tok) << 6) + dh] = f2bf(v);
                    } else if (OUT_MODE == OM_VT) {
                        int b = m / NTOK, tok = m - b * NTOK;
                        int h = n >> 6, dh = n & 63;
                        ((u16*)Cptr)[(((long)b * HEADS + h) * 64 + dh) * SLD + tok] = f2bf(v);
                    } else if (OUT_MODE == OM_S) {
                        ((u16*)Cptr)[(long)g * (NTOK * SLD) + (long)m * SLD + n] = f2bf(v);
                    } else {  // OM_ATTN
                        int b = g / HEADS, h = g - b * HEADS;
                        ((u16*)Cptr)[((long)(b * NTOK + m)) * DIM + h * 64 + n] = f2bf(v);
                    }
                }
            }
        }
    }
}

// ---------------- launch ----------------
extern "C" void kernel_launch(void* const* d_in, const int* in_sizes, int n_in,
                              void* d_out, int out_size, void* d_ws, size_t ws_size,
                              hipStream_t stream) {
    const float* imgs    = (const float*)d_in[0];
    const float* patch_w = (const float*)d_in[1];
    const float* patch_b = (const float*)d_in[2];
    const float* cls_tok = (const float*)d_in[3];
    const float* pos_emb = (const float*)d_in[4];
    const float* ln1_g   = (const float*)d_in[5];
    const float* ln1_b   = (const float*)d_in[6];
    const float* wq      = (const float*)d_in[7];
    const float* bq      = (const float*)d_in[8];
    const float* wk      = (const float*)d_in[9];
    const float* bk      = (const float*)d_in[10];
    const float* wv      = (const float*)d_in[11];
    const float* bv      = (const float*)d_in[12];
    const float* wo      = (const float*)d_in[13];
    const float* bo      = (const float*)d_in[14];
    const float* ln2_g   = (const float*)d_in[15];
    const float* ln2_b   = (const float*)d_in[16];
    const float* w1      = (const float*)d_in[17];
    const float* b1      = (const float*)d_in[18];
    const float* w2      = (const float*)d_in[19];
    const float* b2      = (const float*)d_in[20];
    const float* hn_g    = (const float*)d_in[21];
    const float* hn_b    = (const float*)d_in[22];
    const float* hw      = (const float*)d_in[23];
    const float* hbias   = (const float*)d_in[24];

    char* ws = (char*)d_ws;
    float* x     = (float*)(ws + OFF_X);
    u16*   h     = (u16*)(ws + OFF_H);
    u16*   obuf  = (u16*)(ws + OFF_O);
    u16*   wbuf  = (u16*)(ws + OFF_WB);
    u16*   qbuf  = (u16*)(ws + OFF_Q);
    u16*   kbuf  = (u16*)(ws + OFF_K);
    u16*   vtbuf = (u16*)(ws + OFF_VT);
    u16*   Sbuf  = (u16*)(ws + OFF_S);
    u16*   patchA = (u16*)(ws + OFF_Q);   // reused before layer 0
    u16*   mlph   = (u16*)(ws + OFF_Q);   // reused inside MLP phase
    float* pooled = (float*)(ws + OFF_PL);
    u16*   hb16   = (u16*)(ws + OFF_HB);

    // ---- patch embedding ----
    im2col_kernel<<<(6272 * 768 + 255) / 256, 256, 0, stream>>>(imgs, patchA);
    cast_kernel<<<(589824 + 255) / 256, 256, 0, stream>>>(patch_w, wbuf, 589824);
    gemm_tile<OM_PATCH, EPI_NONE, false><<<dim3(49, 6, 1), 256, 0, stream>>>(
        patchA, wbuf, x, patch_b, 6272, 768, 768, 768, 768, 768, 0, 0, 1.f);
    add_pos_kernel<<<(SROWS * DIM + 255) / 256, 256, 0, stream>>>(x, cls_tok, pos_emb);

    // ---- transformer layers ----
    for (int l = 0; l < LAYERS; ++l) {
        const long wstride = (long)DIM * DIM;
        ln_kernel<<<SROWS, 256, 0, stream>>>(x, ln1_g + l * DIM, ln1_b + l * DIM, h);

        // Q
        transpose_cast<<<dim3(24, 24), 256, 0, stream>>>(wq + l * wstride, wbuf, DIM, DIM);
        gemm_tile<OM_QK, EPI_NONE, false><<<dim3(50, 6, 1), 256, 0, stream>>>(
            h, wbuf, qbuf, bq + l * DIM, SROWS, DIM, DIM, DIM, DIM, 0, 0, 0, 1.f);
        // K
        transpose_cast<<<dim3(24, 24), 256, 0, stream>>>(wk + l * wstride, wbuf, DIM, DIM);
        gemm_tile<OM_QK, EPI_NONE, false><<<dim3(50, 6, 1), 256, 0, stream>>>(
            h, wbuf, kbuf, bk + l * DIM, SROWS, DIM, DIM, DIM, DIM, 0, 0, 0, 1.f);
        // V (stored transposed per head)
        transpose_cast<<<dim3(24, 24), 256, 0, stream>>>(wv + l * wstride, wbuf, DIM, DIM);
        gemm_tile<OM_VT, EPI_NONE, false><<<dim3(50, 6, 1), 256, 0, stream>>>(
            h, wbuf, vtbuf, bv + l * DIM, SROWS, DIM, DIM, DIM, DIM, 0, 0, 0, 1.f);

        // S = QK^T * 1/8  (batched over 384 heads)
        gemm_tile<OM_S, EPI_NONE, false><<<dim3(2, 2, 384), 256, 0, stream>>>(
            qbuf, kbuf, Sbuf, nullptr, NTOK, NTOK, DHEAD, DHEAD, DHEAD, 0,
            (long)NTOK * DHEAD, (long)NTOK * DHEAD, 0.125f);
        softmax_rows<<<(384 * NTOK) / 4, 256, 0, stream>>>(Sbuf);
        // O = P V
        gemm_tile<OM_ATTN, EPI_NONE, false><<<dim3(2, 1, 384), 256, 0, stream>>>(
            Sbuf, vtbuf, obuf, nullptr, NTOK, DHEAD, NTOK, SLD, SLD, 0,
            (long)NTOK * SLD, (long)64 * SLD, 1.f);

        // O projection + residual
        transpose_cast<<<dim3(24, 24), 256, 0, stream>>>(wo + l * wstride, wbuf, DIM, DIM);
        gemm_tile<OM_F32, EPI_NONE, true><<<dim3(50, 6, 1), 256, 0, stream>>>(
            obuf, wbuf, x, bo + l * DIM, SROWS, DIM, DIM, DIM, DIM, DIM, 0, 0, 1.f);

        // MLP
        ln_kernel<<<SROWS, 256, 0, stream>>>(x, ln2_g + l * DIM, ln2_b + l * DIM, h);
        transpose_cast<<<dim3(96, 24), 256, 0, stream>>>(w1 + (long)l * DIM * MLPD, wbuf, DIM, MLPD);
        gemm_tile<OM_BF16, EPI_GELU, false><<<dim3(50, 24, 1), 256, 0, stream>>>(
            h, wbuf, mlph, b1 + l * MLPD, SROWS, MLPD, DIM, DIM, DIM, MLPD, 0, 0, 1.f);
        transpose_cast<<<dim3(24, 96), 256, 0, stream>>>(w2 + (long)l * MLPD * DIM, wbuf, MLPD, DIM);
        gemm_tile<OM_F32, EPI_NONE, true><<<dim3(50, 6, 1), 256, 0, stream>>>(
            mlph, wbuf, x, b2 + l * DIM, SROWS, DIM, MLPD, MLPD, MLPD, DIM, 0, 0, 1.f);
    }

    // ---- head ----
    mean_pool_kernel<<<(BATCH * DIM + 255) / 256, 256, 0, stream>>>(x, pooled);
    ln_kernel<<<BATCH, 256, 0, stream>>>(pooled, hn_g, hn_b, hb16);
    head_kernel<<<BATCH, 256, 0, stream>>>(hb16, hw, hbias, (float*)d_out);
}

// Round 2
// 5665.656 us; speedup vs baseline: 1.2427x; 1.2427x over previous
//
#include <hip/hip_runtime.h>
#include <hip/hip_bf16.h>

typedef unsigned short u16;
typedef __bf16 bf16x8 __attribute__((ext_vector_type(8)));
typedef float f32x4 __attribute__((ext_vector_type(4)));

// ---------------- constants ----------------
#define BATCH 32
#define NTOK 197       // 196 patches + cls
#define DIM 768
#define LAYERS 12
#define HEADS 12
#define DHEAD 64
#define MLPD 3072
#define NCLS 1000
#define SROWS 6304     // BATCH*NTOK
#define SLD 224        // padded attention row stride (multiple of 32 for BK)

// workspace offsets (bytes), all 256-aligned
constexpr long OFF_X  = 0;                      // fp32 residual [6304,768]
constexpr long OFF_H  = 19365888;               // bf16 LN out  [6304,768]
constexpr long OFF_O  = 29048832;               // bf16 attn out [6304,768]
constexpr long OFF_WB = 38731776;               // bf16 weight scratch [3072*768]
constexpr long OFF_Q  = 43450368;               // bf16 q [384,197,64]  (also patchA / mlp_h)
constexpr long OFF_K  = 53133312;               // bf16 k [384,197,64]
constexpr long OFF_VT = 62816256;               // bf16 v^T [384,64,224]
constexpr long OFF_S  = 73826304;               // bf16 S [384,197,224] -> end 107,716,608
constexpr long OFF_PL = OFF_WB;                 // fp32 pooled [32,768] (wbuf dead at head)
constexpr long OFF_HB = OFF_WB + 98304;         // bf16 head LN out [32,768]

// ---------------- helpers ----------------
__device__ inline u16 f2bf(float f) {
    __hip_bfloat16 h = __float2bfloat16(f);
    return __builtin_bit_cast(u16, h);
}
__device__ inline float bf2f(u16 u) {
    unsigned int x = ((unsigned int)u) << 16;
    return __builtin_bit_cast(float, x);
}
// async 16B global->LDS DMA; lds base must be wave-uniform, lane writes base+lane*16
__device__ inline void async16(const u16* g, u16* l) {
    __builtin_amdgcn_global_load_lds(
        (const __attribute__((address_space(1))) void*)g,
        (__attribute__((address_space(3))) void*)l, 16, 0, 0);
}

// ---------------- small kernels ----------------
__global__ __launch_bounds__(256) void im2col_kernel(
        const float* __restrict__ imgs, u16* __restrict__ out) {
    int idx = blockIdx.x * 256 + threadIdx.x;          // 6272*768
    if (idx >= 6272 * 768) return;
    int col = idx % 768, row = idx / 768;
    int b = row / 196, p = row % 196;
    int py = p / 14, px = p % 14;
    int c = col >> 8, ph = (col >> 4) & 15, pw = col & 15;
    float v = imgs[(((long)b * 3 + c) * 224 + (py * 16 + ph)) * 224 + (px * 16 + pw)];
    out[idx] = f2bf(v);
}

__global__ __launch_bounds__(256) void cast_kernel(
        const float* __restrict__ in, u16* __restrict__ out, int n) {
    int idx = blockIdx.x * 256 + threadIdx.x;
    if (idx < n) out[idx] = f2bf(in[idx]);
}

__global__ __launch_bounds__(256) void transpose_cast(
        const float* __restrict__ in, u16* __restrict__ out, int R, int C) {
    __shared__ float tile[32][33];
    int bx = blockIdx.x * 32;   // col base
    int by = blockIdx.y * 32;   // row base
    int tx = threadIdx.x & 31, ty = threadIdx.x >> 5;
#pragma unroll
    for (int i = 0; i < 32; i += 8) {
        int r = by + ty + i, c = bx + tx;
        if (r < R && c < C) tile[ty + i][tx] = in[(long)r * C + c];
    }
    __syncthreads();
#pragma unroll
    for (int i = 0; i < 32; i += 8) {
        int c = bx + ty + i, r = by + tx;
        if (r < R && c < C) out[(long)c * R + r] = f2bf(tile[tx][ty + i]);
    }
}

__global__ __launch_bounds__(256) void add_pos_kernel(
        float* __restrict__ x, const float* __restrict__ cls,
        const float* __restrict__ pos) {
    int idx = blockIdx.x * 256 + threadIdx.x;          // 6304*768
    if (idx >= SROWS * DIM) return;
    int d = idx % DIM, row = idx / DIM, n = row % NTOK;
    if (n == 0) x[idx] = cls[d] + pos[d];
    else        x[idx] += pos[(long)n * DIM + d];
}

__device__ inline float block_sum(float v, float* red) {
#pragma unroll
    for (int off = 32; off; off >>= 1) v += __shfl_xor(v, off, 64);
    int w = threadIdx.x >> 6;
    if ((threadIdx.x & 63) == 0) red[w] = v;
    __syncthreads();
    float s = red[0] + red[1] + red[2] + red[3];
    __syncthreads();
    return s;
}

__global__ __launch_bounds__(256) void ln_kernel(
        const float* __restrict__ x, const float* __restrict__ g,
        const float* __restrict__ bt, u16* __restrict__ out) {
    __shared__ float red[4];
    long row = blockIdx.x;
    const float* xr = x + row * DIM;
    int t = threadIdx.x;
    float v0 = xr[t], v1 = xr[t + 256], v2 = xr[t + 512];
    float mean = block_sum(v0 + v1 + v2, red) * (1.f / 768.f);
    float d0 = v0 - mean, d1 = v1 - mean, d2 = v2 - mean;
    float var = block_sum(d0 * d0 + d1 * d1 + d2 * d2, red) * (1.f / 768.f);
    float rs = rsqrtf(var + 1e-5f);
    u16* o = out + row * DIM;
    o[t]       = f2bf(d0 * rs * g[t]       + bt[t]);
    o[t + 256] = f2bf(d1 * rs * g[t + 256] + bt[t + 256]);
    o[t + 512] = f2bf(d2 * rs * g[t + 512] + bt[t + 512]);
}

__global__ __launch_bounds__(256) void softmax_rows(u16* __restrict__ S) {
    int row = blockIdx.x * 4 + (threadIdx.x >> 6);      // 384*197 rows exactly
    int lane = threadIdx.x & 63;
    u16* p = S + (long)row * SLD;
    float v[4];
#pragma unroll
    for (int i = 0; i < 4; i++) {
        int c = lane + i * 64;
        v[i] = (c < NTOK) ? bf2f(p[c]) : -1e30f;
    }
    float mx = fmaxf(fmaxf(v[0], v[1]), fmaxf(v[2], v[3]));
#pragma unroll
    for (int off = 32; off; off >>= 1) mx = fmaxf(mx, __shfl_xor(mx, off, 64));
    float s = 0.f;
#pragma unroll
    for (int i = 0; i < 4; i++) {
        v[i] = (v[i] > -1e29f) ? __expf(v[i] - mx) : 0.f;
        s += v[i];
    }
#pragma unroll
    for (int off = 32; off; off >>= 1) s += __shfl_xor(s, off, 64);
    float inv = 1.f / s;
#pragma unroll
    for (int i = 0; i < 4; i++) {
        int c = lane + i * 64;
        if (c < NTOK) p[c] = f2bf(v[i] * inv);
    }
}

__global__ __launch_bounds__(256) void mean_pool_kernel(
        const float* __restrict__ x, float* __restrict__ pooled) {
    int idx = blockIdx.x * 256 + threadIdx.x;          // 32*768
    if (idx >= BATCH * DIM) return;
    int b = idx / DIM, d = idx % DIM;
    float s = 0.f;
    for (int n = 0; n < NTOK; n++) s += x[((long)b * NTOK + n) * DIM + d];
    pooled[idx] = s * (1.f / 197.f);
}

__global__ __launch_bounds__(256) void head_kernel(
        const u16* __restrict__ hx, const float* __restrict__ hw,
        const float* __restrict__ hb, float* __restrict__ out) {
    __shared__ float xr[DIM];
    int b = blockIdx.x;
    for (int i = threadIdx.x; i < DIM; i += 256) xr[i] = bf2f(hx[b * DIM + i]);
    __syncthreads();
    for (int c = threadIdx.x; c < NCLS; c += 256) {
        float s = hb[c];
        for (int d = 0; d < DIM; d++) s += xr[d] * hw[(long)d * NCLS + c];
        out[b * NCLS + c] = s;
    }
}

// ---------------- MFMA GEMM (m97-style async staging) ----------------
// C[M,N] = A[M,K](bf16,row-major,lda) * B^T, B stored [N,K](bf16,ldb).
// Tile TM x TN x BK=32. 4 waves: TN==128 -> 2x2 of 64x64; TN==64 -> 4x1 of 64x64.
// LDS unpadded [rows][32] bf16 (global_load_lds requires base+lane*16 layout).
// Row indices clamped (no per-lane guards); K must be a multiple of 32.
constexpr int OM_F32 = 0, OM_BF16 = 1, OM_PATCH = 2, OM_QK = 3, OM_VT = 4,
              OM_S = 5, OM_ATTN = 6;
constexpr int EPI_NONE = 0, EPI_GELU = 1;

template<int TM, int TN, int OUT_MODE, int EPI, bool RESID>
__global__ __launch_bounds__(256, 2) void gemm_async(
        const u16* __restrict__ Aall, const u16* __restrict__ Ball,
        void* __restrict__ Cptr, const float* __restrict__ bias,
        int M, int N, int K, int lda, int ldb, int ldc,
        long sA, long sB, float scale) {
    __shared__ u16 As[TM * 32];
    __shared__ u16 Bs[TN * 32];
    int g = blockIdx.z;
    const u16* A = Aall + (long)g * sA;
    const u16* B = Ball + (long)g * sB;
    int m0 = blockIdx.x * TM;
    int n0 = blockIdx.y * TN;
    int tid = threadIdx.x;
    int lane = tid & 63;
    int wave = tid >> 6;
    int wm, wn;
    if (TN == 128) { wm = (wave & 1) * 64; wn = (wave >> 1) * 64; }
    else           { wm = wave * 64;       wn = 0; }
    int lm = lane & 15;
    int lq = lane >> 4;

    f32x4 acc[4][4];
    const f32x4 z4 = {0.f, 0.f, 0.f, 0.f};
#pragma unroll
    for (int i = 0; i < 4; i++)
#pragma unroll
        for (int j = 0; j < 4; j++) acc[i][j] = z4;

    int rsub = lane >> 2;            // 0..15 row within 16-row chunk
    int ksub = (lane & 3) * 8;       // 0,8,16,24 (x8 bf16 = 16B)

    for (int k0 = 0; k0 < K; k0 += 32) {
#pragma unroll
        for (int c = 0; c < TM / 64; c++) {
            int row = c * 64 + wave * 16;            // wave-uniform chunk base
            int gr = m0 + row + rsub;
            gr = gr < M ? gr : M - 1;
            async16(A + (long)gr * lda + k0 + ksub, &As[row * 32]);
        }
#pragma unroll
        for (int c = 0; c < TN / 64; c++) {
            int row = c * 64 + wave * 16;
            int gn = n0 + row + rsub;
            gn = gn < N ? gn : N - 1;
            async16(B + (long)gn * ldb + k0 + ksub, &Bs[row * 32]);
        }
        __syncthreads();
        bf16x8 af[4], bfr[4];
#pragma unroll
        for (int i = 0; i < 4; i++)
            af[i] = *reinterpret_cast<const bf16x8*>(&As[(wm + i * 16 + lm) * 32 + lq * 8]);
#pragma unroll
        for (int i = 0; i < 4; i++)
            bfr[i] = *reinterpret_cast<const bf16x8*>(&Bs[(wn + i * 16 + lm) * 32 + lq * 8]);
#pragma unroll
        for (int mi = 0; mi < 4; mi++)
#pragma unroll
            for (int ni = 0; ni < 4; ni++)
                acc[mi][ni] = __builtin_amdgcn_mfma_f32_16x16x32_bf16(
                        af[mi], bfr[ni], acc[mi][ni], 0, 0, 0);
        __syncthreads();
    }

    // epilogue: C/D layout col=lane&15, row=(lane>>4)*4+reg
    int nlim = (OUT_MODE == OM_S) ? SLD : N;   // OM_S zero-fills pad cols [N,SLD)
#pragma unroll
    for (int mi = 0; mi < 4; mi++) {
#pragma unroll
        for (int ni = 0; ni < 4; ni++) {
#pragma unroll
            for (int r = 0; r < 4; r++) {
                int m = m0 + wm + mi * 16 + lq * 4 + r;
                int n = n0 + wn + ni * 16 + lm;
                if (m < M && n < nlim) {
                    float v = 0.f;
                    if (!(OUT_MODE == OM_S && n >= N)) {
                        v = acc[mi][ni][r] * scale;
                        if (bias) v += bias[n];
                        if (EPI == EPI_GELU) {
                            float u = v;
                            v = 0.5f * u * (1.f + tanhf(0.7978845608028654f *
                                                        (u + 0.044715f * u * u * u)));
                        }
                    }
                    if (OUT_MODE == OM_F32) {
                        float* Cf = (float*)Cptr;
                        long idx = (long)m * ldc + n;
                        if (RESID) v += Cf[idx];
                        Cf[idx] = v;
                    } else if (OUT_MODE == OM_BF16) {
                        ((u16*)Cptr)[(long)m * ldc + n] = f2bf(v);
                    } else if (OUT_MODE == OM_PATCH) {
                        int row = m + m / 196 + 1;   // skip cls row of each batch
                        ((float*)Cptr)[(long)row * DIM + n] = v;
                    } else if (OUT_MODE == OM_QK) {
                        int b = m / NTOK, tok = m - b * NTOK;
                        int hh = n >> 6, dh = n & 63;
                        ((u16*)Cptr)[((((long)b * HEADS + hh) * NTOK + tok) << 6) + dh] = f2bf(v);
                    } else if (OUT_MODE == OM_VT) {
                        int b = m / NTOK, tok = m - b * NTOK;
                        int hh = n >> 6, dh = n & 63;
                        ((u16*)Cptr)[(((long)b * HEADS + hh) * 64 + dh) * SLD + tok] = f2bf(v);
                    } else if (OUT_MODE == OM_S) {
                        ((u16*)Cptr)[(long)g * (NTOK * SLD) + (long)m * SLD + n] = f2bf(v);
                    } else {  // OM_ATTN
                        int b = g / HEADS, hh = g - b * HEADS;
                        ((u16*)Cptr)[((long)(b * NTOK + m)) * DIM + hh * 64 + n] = f2bf(v);
                    }
                }
            }
        }
    }
}

// ---------------- launch ----------------
extern "C" void kernel_launch(void* const* d_in, const int* in_sizes, int n_in,
                              void* d_out, int out_size, void* d_ws, size_t ws_size,
                              hipStream_t stream) {
    const float* imgs    = (const float*)d_in[0];
    const float* patch_w = (const float*)d_in[1];
    const float* patch_b = (const float*)d_in[2];
    const float* cls_tok = (const float*)d_in[3];
    const float* pos_emb = (const float*)d_in[4];
    const float* ln1_g   = (const float*)d_in[5];
    const float* ln1_b   = (const float*)d_in[6];
    const float* wq      = (const float*)d_in[7];
    const float* bq      = (const float*)d_in[8];
    const float* wk      = (const float*)d_in[9];
    const float* bk      = (const float*)d_in[10];
    const float* wv      = (const float*)d_in[11];
    const float* bv      = (const float*)d_in[12];
    const float* wo      = (const float*)d_in[13];
    const float* bo      = (const float*)d_in[14];
    const float* ln2_g   = (const float*)d_in[15];
    const float* ln2_b   = (const float*)d_in[16];
    const float* w1      = (const float*)d_in[17];
    const float* b1      = (const float*)d_in[18];
    const float* w2      = (const float*)d_in[19];
    const float* b2      = (const float*)d_in[20];
    const float* hn_g    = (const float*)d_in[21];
    const float* hn_b    = (const float*)d_in[22];
    const float* hw      = (const float*)d_in[23];
    const float* hbias   = (const float*)d_in[24];

    char* ws = (char*)d_ws;
    float* x     = (float*)(ws + OFF_X);
    u16*   h     = (u16*)(ws + OFF_H);
    u16*   obuf  = (u16*)(ws + OFF_O);
    u16*   wbuf  = (u16*)(ws + OFF_WB);
    u16*   qbuf  = (u16*)(ws + OFF_Q);
    u16*   kbuf  = (u16*)(ws + OFF_K);
    u16*   vtbuf = (u16*)(ws + OFF_VT);
    u16*   Sbuf  = (u16*)(ws + OFF_S);
    u16*   patchA = (u16*)(ws + OFF_Q);   // reused before layer 0
    u16*   mlph   = (u16*)(ws + OFF_Q);   // reused inside MLP phase (spans into K/VT/S: dead then)
    float* pooled = (float*)(ws + OFF_PL);
    u16*   hb16   = (u16*)(ws + OFF_HB);

    // ---- patch embedding ----
    im2col_kernel<<<(6272 * 768 + 255) / 256, 256, 0, stream>>>(imgs, patchA);
    cast_kernel<<<(589824 + 255) / 256, 256, 0, stream>>>(patch_w, wbuf, 589824);
    gemm_async<128, 128, OM_PATCH, EPI_NONE, false><<<dim3(49, 6, 1), 256, 0, stream>>>(
        patchA, wbuf, x, patch_b, 6272, 768, 768, 768, 768, 768, 0, 0, 1.f);
    add_pos_kernel<<<(SROWS * DIM + 255) / 256, 256, 0, stream>>>(x, cls_tok, pos_emb);

    // ---- transformer layers ----
    for (int l = 0; l < LAYERS; ++l) {
        const long wstride = (long)DIM * DIM;
        ln_kernel<<<SROWS, 256, 0, stream>>>(x, ln1_g + l * DIM, ln1_b + l * DIM, h);

        // Q
        transpose_cast<<<dim3(24, 24), 256, 0, stream>>>(wq + l * wstride, wbuf, DIM, DIM);
        gemm_async<128, 128, OM_QK, EPI_NONE, false><<<dim3(50, 6, 1), 256, 0, stream>>>(
            h, wbuf, qbuf, bq + l * DIM, SROWS, DIM, DIM, DIM, DIM, 0, 0, 0, 1.f);
        // K
        transpose_cast<<<dim3(24, 24), 256, 0, stream>>>(wk + l * wstride, wbuf, DIM, DIM);
        gemm_async<128, 128, OM_QK, EPI_NONE, false><<<dim3(50, 6, 1), 256, 0, stream>>>(
            h, wbuf, kbuf, bk + l * DIM, SROWS, DIM, DIM, DIM, DIM, 0, 0, 0, 1.f);
        // V (stored transposed per head, padded to SLD)
        transpose_cast<<<dim3(24, 24), 256, 0, stream>>>(wv + l * wstride, wbuf, DIM, DIM);
        gemm_async<128, 128, OM_VT, EPI_NONE, false><<<dim3(50, 6, 1), 256, 0, stream>>>(
            h, wbuf, vtbuf, bv + l * DIM, SROWS, DIM, DIM, DIM, DIM, 0, 0, 0, 1.f);

        // S = QK^T * 1/8  (batched over 384 heads), pad cols zeroed
        gemm_async<128, 128, OM_S, EPI_NONE, false><<<dim3(2, 2, 384), 256, 0, stream>>>(
            qbuf, kbuf, Sbuf, nullptr, NTOK, NTOK, DHEAD, DHEAD, DHEAD, 0,
            (long)NTOK * DHEAD, (long)NTOK * DHEAD, 0.125f);
        softmax_rows<<<(384 * NTOK) / 4, 256, 0, stream>>>(Sbuf);
        // O = P V  (K padded to SLD=224, S pad cols are exact zeros)
        gemm_async<256, 64, OM_ATTN, EPI_NONE, false><<<dim3(1, 1, 384), 256, 0, stream>>>(
            Sbuf, vtbuf, obuf, nullptr, NTOK, DHEAD, SLD, SLD, SLD, 0,
            (long)NTOK * SLD, (long)64 * SLD, 1.f);

        // O projection + residual
        transpose_cast<<<dim3(24, 24), 256, 0, stream>>>(wo + l * wstride, wbuf, DIM, DIM);
        gemm_async<128, 128, OM_F32, EPI_NONE, true><<<dim3(50, 6, 1), 256, 0, stream>>>(
            obuf, wbuf, x, bo + l * DIM, SROWS, DIM, DIM, DIM, DIM, DIM, 0, 0, 1.f);

        // MLP
        ln_kernel<<<SROWS, 256, 0, stream>>>(x, ln2_g + l * DIM, ln2_b + l * DIM, h);
        transpose_cast<<<dim3(96, 24), 256, 0, stream>>>(w1 + (long)l * DIM * MLPD, wbuf, DIM, MLPD);
        gemm_async<128, 128, OM_BF16, EPI_GELU, false><<<dim3(50, 24, 1), 256, 0, stream>>>(
            h, wbuf, mlph, b1 + l * MLPD, SROWS, MLPD, DIM, DIM, DIM, MLPD, 0, 0, 1.f);
        transpose_cast<<<dim3(24, 96), 256, 0, stream>>>(w2 + (long)l * MLPD * DIM, wbuf, MLPD, DIM);
        gemm_async<128, 128, OM_F32, EPI_NONE, true><<<dim3(50, 6, 1), 256, 0, stream>>>(
            mlph, wbuf, x, b2 + l * DIM, SROWS, DIM, MLPD, MLPD, MLPD, DIM, 0, 0, 1.f);
    }

    // ---- head ----
    mean_pool_kernel<<<(BATCH * DIM + 255) / 256, 256, 0, stream>>>(x, pooled);
    ln_kernel<<<BATCH, 256, 0, stream>>>(pooled, hn_g, hn_b, hb16);
    head_kernel<<<BATCH, 256, 0, stream>>>(hb16, hw, hbias, (float*)d_out);
}

// Round 4
// 4638.217 us; speedup vs baseline: 1.5180x; 1.2215x over previous
//
#include <hip/hip_runtime.h>
#include <hip/hip_bf16.h>

typedef unsigned short u16;
typedef __bf16 bf16x8 __attribute__((ext_vector_type(8)));
typedef float f32x4 __attribute__((ext_vector_type(4)));

// ---------------- constants ----------------
#define BATCH 32
#define NTOK 197       // 196 patches + cls
#define DIM 768
#define LAYERS 12
#define HEADS 12
#define DHEAD 64
#define MLPD 3072
#define NCLS 1000
#define SROWS 6304     // BATCH*NTOK
#define SLD 224        // padded V^T row stride (multiple of 32)
#define PLD 232        // P LDS row stride: 464B = 29x16 -> 16B-aligned b128 rows

// workspace offsets (bytes), all 256-aligned
constexpr long OFF_X  = 0;                      // fp32 residual [6304,768]
constexpr long OFF_H  = 19365888;               // bf16 LN out  [6304,768]
constexpr long OFF_O  = 29048832;               // bf16 attn out [6304,768]
constexpr long OFF_WB = 38731776;               // bf16 weight scratch (4.72 MB)
constexpr long OFF_Q  = 43450368;               // bf16 q [384,197,64] (also patchA / mlp_h)
constexpr long OFF_K  = 53133312;               // bf16 k [384,197,64]
constexpr long OFF_VT = 62816256;               // bf16 v^T [384,64,224]
constexpr long OFF_PL = OFF_WB;                 // fp32 pooled [32,768] (wbuf dead at head)
constexpr long OFF_HB = OFF_WB + 98304;         // bf16 head LN out [32,768]
// q/k/vt element offsets from qbuf base (u16 units)
constexpr long QK_SEG = 4841472;                // 384*197*64

// ---------------- helpers ----------------
__device__ inline u16 f2bf(float f) {
    __hip_bfloat16 h = __float2bfloat16(f);
    return __builtin_bit_cast(u16, h);
}
__device__ inline float bf2f(u16 u) {
    unsigned int x = ((unsigned int)u) << 16;
    return __builtin_bit_cast(float, x);
}
// async 16B global->LDS DMA; lds base must be wave-uniform, lane writes base+lane*16
__device__ inline void async16(const u16* g, u16* l) {
    __builtin_amdgcn_global_load_lds(
        (const __attribute__((address_space(1))) void*)g,
        (__attribute__((address_space(3))) void*)l, 16, 0, 0);
}

// ---------------- small kernels ----------------
__global__ __launch_bounds__(256) void im2col_kernel(
        const float* __restrict__ imgs, u16* __restrict__ out) {
    int idx = blockIdx.x * 256 + threadIdx.x;          // 6272*768
    if (idx >= 6272 * 768) return;
    int col = idx % 768, row = idx / 768;
    int b = row / 196, p = row % 196;
    int py = p / 14, px = p % 14;
    int c = col >> 8, ph = (col >> 4) & 15, pw = col & 15;
    float v = imgs[(((long)b * 3 + c) * 224 + (py * 16 + ph)) * 224 + (px * 16 + pw)];
    out[idx] = f2bf(v);
}

__global__ __launch_bounds__(256) void cast_kernel(
        const float* __restrict__ in, u16* __restrict__ out, int n) {
    int idx = blockIdx.x * 256 + threadIdx.x;
    if (idx < n) out[idx] = f2bf(in[idx]);
}

__global__ __launch_bounds__(256) void transpose_cast(
        const float* __restrict__ in, u16* __restrict__ out, int R, int C) {
    __shared__ float tile[32][33];
    int bx = blockIdx.x * 32, by = blockIdx.y * 32;
    int tx = threadIdx.x & 31, ty = threadIdx.x >> 5;
#pragma unroll
    for (int i = 0; i < 32; i += 8) {
        int r = by + ty + i, c = bx + tx;
        if (r < R && c < C) tile[ty + i][tx] = in[(long)r * C + c];
    }
    __syncthreads();
#pragma unroll
    for (int i = 0; i < 32; i += 8) {
        int c = bx + ty + i, r = by + tx;
        if (r < R && c < C) out[(long)c * R + r] = f2bf(tile[tx][ty + i]);
    }
}

// 4 square matrices (768x768) transposed in one dispatch, z selects source
__global__ __launch_bounds__(256) void transpose_cast4(
        const float* __restrict__ p0, const float* __restrict__ p1,
        const float* __restrict__ p2, const float* __restrict__ p3,
        u16* __restrict__ out) {
    __shared__ float tile[32][33];
    int z = blockIdx.z;
    const float* in = z == 0 ? p0 : z == 1 ? p1 : z == 2 ? p2 : p3;
    u16* o = out + (long)z * DIM * DIM;
    int bx = blockIdx.x * 32, by = blockIdx.y * 32;
    int tx = threadIdx.x & 31, ty = threadIdx.x >> 5;
#pragma unroll
    for (int i = 0; i < 32; i += 8)
        tile[ty + i][tx] = in[(long)(by + ty + i) * DIM + bx + tx];
    __syncthreads();
#pragma unroll
    for (int i = 0; i < 32; i += 8)
        o[(long)(bx + ty + i) * DIM + by + tx] = f2bf(tile[tx][ty + i]);
}

__global__ __launch_bounds__(256) void add_pos_kernel(
        float* __restrict__ x, const float* __restrict__ cls,
        const float* __restrict__ pos) {
    int idx = blockIdx.x * 256 + threadIdx.x;          // 6304*768
    if (idx >= SROWS * DIM) return;
    int d = idx % DIM, row = idx / DIM, n = row % NTOK;
    if (n == 0) x[idx] = cls[d] + pos[d];
    else        x[idx] += pos[(long)n * DIM + d];
}

__device__ inline float block_sum(float v, float* red) {
#pragma unroll
    for (int off = 32; off; off >>= 1) v += __shfl_xor(v, off, 64);
    int w = threadIdx.x >> 6;
    if ((threadIdx.x & 63) == 0) red[w] = v;
    __syncthreads();
    float s = red[0] + red[1] + red[2] + red[3];
    __syncthreads();
    return s;
}

__global__ __launch_bounds__(256) void ln_kernel(
        const float* __restrict__ x, const float* __restrict__ g,
        const float* __restrict__ bt, u16* __restrict__ out) {
    __shared__ float red[4];
    long row = blockIdx.x;
    const float* xr = x + row * DIM;
    int t = threadIdx.x;
    float v0 = xr[t], v1 = xr[t + 256], v2 = xr[t + 512];
    float mean = block_sum(v0 + v1 + v2, red) * (1.f / 768.f);
    float d0 = v0 - mean, d1 = v1 - mean, d2 = v2 - mean;
    float var = block_sum(d0 * d0 + d1 * d1 + d2 * d2, red) * (1.f / 768.f);
    float rs = rsqrtf(var + 1e-5f);
    u16* o = out + row * DIM;
    o[t]       = f2bf(d0 * rs * g[t]       + bt[t]);
    o[t + 256] = f2bf(d1 * rs * g[t + 256] + bt[t + 256]);
    o[t + 512] = f2bf(d2 * rs * g[t + 512] + bt[t + 512]);
}

__global__ __launch_bounds__(256) void mean_pool_kernel(
        const float* __restrict__ x, float* __restrict__ pooled) {
    int idx = blockIdx.x * 256 + threadIdx.x;          // 32*768
    if (idx >= BATCH * DIM) return;
    int b = idx / DIM, d = idx % DIM;
    float s = 0.f;
    for (int n = 0; n < NTOK; n++) s += x[((long)b * NTOK + n) * DIM + d];
    pooled[idx] = s * (1.f / 197.f);
}

// parallel head: grid (32, 4); block computes 256 columns of one batch row
__global__ __launch_bounds__(256) void head_kernel(
        const u16* __restrict__ hx, const float* __restrict__ hw,
        const float* __restrict__ hb, float* __restrict__ out) {
    __shared__ float xr[DIM];
    int b = blockIdx.x;
    for (int i = threadIdx.x; i < DIM; i += 256) xr[i] = bf2f(hx[b * DIM + i]);
    __syncthreads();
    int c = blockIdx.y * 256 + threadIdx.x;
    if (c < NCLS) {
        float s = hb[c];
        for (int d = 0; d < DIM; d++) s += xr[d] * hw[(long)d * NCLS + c];
        out[b * NCLS + c] = s;
    }
}

// ---------------- MFMA GEMM (async staging) ----------------
// C[M,N] = A[M,K](bf16,row-major,lda) * B^T, B stored [N,K](bf16,ldb).
// 128x128 tile, BK=32, 4 waves 2x2 of 64x64. K multiple of 32; rows clamped.
constexpr int OM_F32 = 0, OM_BF16 = 1, OM_PATCH = 2, OM_QKV = 3;
constexpr int EPI_NONE = 0, EPI_GELU = 1;

template<int OUT_MODE, int EPI, bool RESID>
__global__ __launch_bounds__(256, 2) void gemm_async(
        const u16* __restrict__ A, const u16* __restrict__ B,
        void* __restrict__ Cptr, const float* __restrict__ bias,
        const float* __restrict__ bias2, const float* __restrict__ bias3,
        int M, int N, int K, int lda, int ldb, int ldc) {
    __shared__ u16 As[128 * 32];
    __shared__ u16 Bs[128 * 32];
    int m0 = blockIdx.x * 128;
    int n0 = blockIdx.y * 128;
    int tid = threadIdx.x;
    int lane = tid & 63;
    int wave = tid >> 6;
    int wm = (wave & 1) * 64;
    int wn = (wave >> 1) * 64;
    int lm = lane & 15;
    int lq = lane >> 4;

    f32x4 acc[4][4];
    const f32x4 z4 = {0.f, 0.f, 0.f, 0.f};
#pragma unroll
    for (int i = 0; i < 4; i++)
#pragma unroll
        for (int j = 0; j < 4; j++) acc[i][j] = z4;

    int rsub = lane >> 2;            // 0..15
    int ksub = (lane & 3) * 8;       // 0,8,16,24

    for (int k0 = 0; k0 < K; k0 += 32) {
#pragma unroll
        for (int c = 0; c < 2; c++) {
            int row = c * 64 + wave * 16;
            int gr = m0 + row + rsub; gr = gr < M ? gr : M - 1;
            async16(A + (long)gr * lda + k0 + ksub, &As[row * 32]);
            int gn = n0 + row + rsub; gn = gn < N ? gn : N - 1;
            async16(B + (long)gn * ldb + k0 + ksub, &Bs[row * 32]);
        }
        __syncthreads();
        bf16x8 af[4], bfr[4];
#pragma unroll
        for (int i = 0; i < 4; i++)
            af[i] = *reinterpret_cast<const bf16x8*>(&As[(wm + i * 16 + lm) * 32 + lq * 8]);
#pragma unroll
        for (int i = 0; i < 4; i++)
            bfr[i] = *reinterpret_cast<const bf16x8*>(&Bs[(wn + i * 16 + lm) * 32 + lq * 8]);
#pragma unroll
        for (int mi = 0; mi < 4; mi++)
#pragma unroll
            for (int ni = 0; ni < 4; ni++)
                acc[mi][ni] = __builtin_amdgcn_mfma_f32_16x16x32_bf16(
                        af[mi], bfr[ni], acc[mi][ni], 0, 0, 0);
        __syncthreads();
    }

    // epilogue: C/D layout col=lane&15, row=(lane>>4)*4+reg
#pragma unroll
    for (int mi = 0; mi < 4; mi++) {
#pragma unroll
        for (int ni = 0; ni < 4; ni++) {
#pragma unroll
            for (int r = 0; r < 4; r++) {
                int m = m0 + wm + mi * 16 + lq * 4 + r;
                int n = n0 + wn + ni * 16 + lm;
                if (m < M && n < N) {
                    float v = acc[mi][ni][r];
                    if (OUT_MODE == OM_QKV) {
                        int seg = n >= 1536 ? 2 : (n >= 768 ? 1 : 0);
                        int nn = n - seg * 768;
                        const float* bp = seg == 0 ? bias : seg == 1 ? bias2 : bias3;
                        v += bp[nn];
                        int b = m / NTOK, tok = m - b * NTOK;
                        int hh = nn >> 6, dh = nn & 63;
                        u16* base = (u16*)Cptr;
                        if (seg < 2)
                            base[(long)seg * QK_SEG +
                                 ((((long)b * HEADS + hh) * NTOK + tok) << 6) + dh] = f2bf(v);
                        else
                            base[2 * QK_SEG +
                                 (((long)b * HEADS + hh) * 64 + dh) * SLD + tok] = f2bf(v);
                    } else {
                        if (bias) v += bias[n];
                        if (EPI == EPI_GELU) {
                            float u = v;
                            v = 0.5f * u * (1.f + tanhf(0.7978845608028654f *
                                                        (u + 0.044715f * u * u * u)));
                        }
                        if (OUT_MODE == OM_F32) {
                            float* Cf = (float*)Cptr;
                            long idx = (long)m * ldc + n;
                            if (RESID) v += Cf[idx];
                            Cf[idx] = v;
                        } else if (OUT_MODE == OM_BF16) {
                            ((u16*)Cptr)[(long)m * ldc + n] = f2bf(v);
                        } else {  // OM_PATCH
                            int row = m + m / 196 + 1;   // skip cls row of each batch
                            ((float*)Cptr)[(long)row * DIM + n] = v;
                        }
                    }
                }
            }
        }
    }
}

// ---------------- fused attention ----------------
// grid (4, 384): q-tile t (64 rows) x head g. Per block:
//   S = Q K^T/8 (in-register), softmax (LDS cross-wave reduce), P->LDS, O = P V.
// LDS map (bytes): As 0..8192 [2][64][32], Bs 8192..40960 [2][256][32],
//   Vs 40960..69632 [64][224], red 69632..71680 (512 floats),
//   Ps 0..29696 [64][PLD=232] (reuses As/Bs after barrier).
__global__ __launch_bounds__(256) void attn_fused(
        const u16* __restrict__ qbuf, const u16* __restrict__ kbuf,
        const u16* __restrict__ vtbuf, u16* __restrict__ obuf) {
    __shared__ char smem[71680];
    u16* As = (u16*)smem;
    u16* Bs = (u16*)(smem + 8192);
    u16* Vs = (u16*)(smem + 40960);
    float* red = (float*)(smem + 69632);          // 69632..71680, no overlap with Vs
    u16* Ps = (u16*)smem;

    int t = blockIdx.x, g = blockIdx.y;
    int q0 = t * 64;
    const u16* Q  = qbuf  + (long)g * NTOK * DHEAD;
    const u16* Kp = kbuf  + (long)g * NTOK * DHEAD;
    const u16* Vt = vtbuf + (long)g * DHEAD * SLD;
    int tid = threadIdx.x, lane = tid & 63, wave = tid >> 6;
    int lm = lane & 15, lq = lane >> 4;
    int rsub = lane >> 2, ksub = (lane & 3) * 8;

    // stage Q (64 rows), K (256 rows clamped), V^T (linear 28 KB)
#pragma unroll
    for (int kh = 0; kh < 2; kh++) {
        int gr = q0 + wave * 16 + rsub; gr = gr < NTOK ? gr : NTOK - 1;
        async16(Q + (long)gr * DHEAD + kh * 32 + ksub, &As[kh * 2048 + wave * 16 * 32]);
#pragma unroll
        for (int c = 0; c < 4; c++) {
            int gk = c * 64 + wave * 16 + rsub; gk = gk < NTOK ? gk : NTOK - 1;
            async16(Kp + (long)gk * DHEAD + kh * 32 + ksub,
                    &Bs[kh * 8192 + (c * 64 + wave * 16) * 32]);
        }
    }
#pragma unroll
    for (int cc = 0; cc < 7; cc++) {
        int c = cc * 4 + wave;
        async16(Vt + c * 512 + lane * 8, &Vs[c * 512]);
    }
    __syncthreads();

    // S = Q K^T: rows 0..63 (all waves), cols wave*64 + ni*16+lm
    f32x4 acc[4][4];
    const f32x4 z4 = {0.f, 0.f, 0.f, 0.f};
#pragma unroll
    for (int i = 0; i < 4; i++)
#pragma unroll
        for (int j = 0; j < 4; j++) acc[i][j] = z4;
#pragma unroll
    for (int kh = 0; kh < 2; kh++) {
        bf16x8 af[4], bfr[4];
#pragma unroll
        for (int mi = 0; mi < 4; mi++)
            af[mi] = *reinterpret_cast<const bf16x8*>(
                &As[kh * 2048 + (mi * 16 + lm) * 32 + lq * 8]);
#pragma unroll
        for (int ni = 0; ni < 4; ni++)
            bfr[ni] = *reinterpret_cast<const bf16x8*>(
                &Bs[kh * 8192 + (wave * 64 + ni * 16 + lm) * 32 + lq * 8]);
#pragma unroll
        for (int mi = 0; mi < 4; mi++)
#pragma unroll
            for (int ni = 0; ni < 4; ni++)
                acc[mi][ni] = __builtin_amdgcn_mfma_f32_16x16x32_bf16(
                        af[mi], bfr[ni], acc[mi][ni], 0, 0, 0);
    }

    // scale + mask, then row-max partial per wave
#pragma unroll
    for (int mi = 0; mi < 4; mi++)
#pragma unroll
        for (int ni = 0; ni < 4; ni++) {
            int n = wave * 64 + ni * 16 + lm;
#pragma unroll
            for (int r = 0; r < 4; r++)
                acc[mi][ni][r] = (n < NTOK) ? acc[mi][ni][r] * 0.125f : -1e30f;
        }
#pragma unroll
    for (int mi = 0; mi < 4; mi++)
#pragma unroll
        for (int r = 0; r < 4; r++) {
            float mp = fmaxf(fmaxf(acc[mi][0][r], acc[mi][1][r]),
                             fmaxf(acc[mi][2][r], acc[mi][3][r]));
#pragma unroll
            for (int o = 1; o < 16; o <<= 1) mp = fmaxf(mp, __shfl_xor(mp, o));
            if (lm == 0) red[wave * 64 + mi * 16 + lq * 4 + r] = mp;
        }
    __syncthreads();
    // exp + row-sum partial
#pragma unroll
    for (int mi = 0; mi < 4; mi++)
#pragma unroll
        for (int r = 0; r < 4; r++) {
            int row = mi * 16 + lq * 4 + r;
            float M = fmaxf(fmaxf(red[row], red[64 + row]),
                            fmaxf(red[128 + row], red[192 + row]));
            float sp = 0.f;
#pragma unroll
            for (int ni = 0; ni < 4; ni++) {
                float e = __expf(acc[mi][ni][r] - M);
                acc[mi][ni][r] = e;
                sp += e;
            }
#pragma unroll
            for (int o = 1; o < 16; o <<= 1) sp += __shfl_xor(sp, o);
            if (lm == 0) red[256 + wave * 64 + row] = sp;
        }
    __syncthreads();
    // normalize, write P to LDS (pad cols zeroed); overwrites As/Bs (safe: post-barrier)
#pragma unroll
    for (int mi = 0; mi < 4; mi++)
#pragma unroll
        for (int r = 0; r < 4; r++) {
            int row = mi * 16 + lq * 4 + r;
            float s = red[256 + row] + red[256 + 64 + row] +
                      red[256 + 128 + row] + red[256 + 192 + row];
            float inv = 1.f / s;
#pragma unroll
            for (int ni = 0; ni < 4; ni++) {
                int n = wave * 64 + ni * 16 + lm;
                if (n < PLD) Ps[row * PLD + n] = f2bf(acc[mi][ni][r] * inv);
            }
        }
    __syncthreads();

    // O = P V: wave w computes rows w*16..w*16+15, cols 0..63
    f32x4 pacc[4];
#pragma unroll
    for (int i = 0; i < 4; i++) pacc[i] = z4;
    for (int k0 = 0; k0 < SLD; k0 += 32) {
        bf16x8 paf = *reinterpret_cast<const bf16x8*>(
            &Ps[(wave * 16 + lm) * PLD + k0 + lq * 8]);
        bf16x8 pbf[4];
#pragma unroll
        for (int ni = 0; ni < 4; ni++)
            pbf[ni] = *reinterpret_cast<const bf16x8*>(
                &Vs[(ni * 16 + lm) * SLD + k0 + lq * 8]);
#pragma unroll
        for (int ni = 0; ni < 4; ni++)
            pacc[ni] = __builtin_amdgcn_mfma_f32_16x16x32_bf16(
                    paf, pbf[ni], pacc[ni], 0, 0, 0);
    }
    int b = g / HEADS, hh = g - b * HEADS;
#pragma unroll
    for (int ni = 0; ni < 4; ni++)
#pragma unroll
        for (int r = 0; r < 4; r++) {
            int tok = q0 + wave * 16 + lq * 4 + r;
            if (tok < NTOK)
                obuf[((long)(b * NTOK + tok)) * DIM + hh * 64 + ni * 16 + lm] =
                    f2bf(pacc[ni][r]);
        }
}

// ---------------- launch ----------------
extern "C" void kernel_launch(void* const* d_in, const int* in_sizes, int n_in,
                              void* d_out, int out_size, void* d_ws, size_t ws_size,
                              hipStream_t stream) {
    const float* imgs    = (const float*)d_in[0];
    const float* patch_w = (const float*)d_in[1];
    const float* patch_b = (const float*)d_in[2];
    const float* cls_tok = (const float*)d_in[3];
    const float* pos_emb = (const float*)d_in[4];
    const float* ln1_g   = (const float*)d_in[5];
    const float* ln1_b   = (const float*)d_in[6];
    const float* wq      = (const float*)d_in[7];
    const float* bq      = (const float*)d_in[8];
    const float* wk      = (const float*)d_in[9];
    const float* bk      = (const float*)d_in[10];
    const float* wv      = (const float*)d_in[11];
    const float* bv      = (const float*)d_in[12];
    const float* wo      = (const float*)d_in[13];
    const float* bo      = (const float*)d_in[14];
    const float* ln2_g   = (const float*)d_in[15];
    const float* ln2_b   = (const float*)d_in[16];
    const float* w1      = (const float*)d_in[17];
    const float* b1      = (const float*)d_in[18];
    const float* w2      = (const float*)d_in[19];
    const float* b2      = (const float*)d_in[20];
    const float* hn_g    = (const float*)d_in[21];
    const float* hn_b    = (const float*)d_in[22];
    const float* hw      = (const float*)d_in[23];
    const float* hbias   = (const float*)d_in[24];

    char* ws = (char*)d_ws;
    float* x     = (float*)(ws + OFF_X);
    u16*   h     = (u16*)(ws + OFF_H);
    u16*   obuf  = (u16*)(ws + OFF_O);
    u16*   wbuf  = (u16*)(ws + OFF_WB);
    u16*   qbuf  = (u16*)(ws + OFF_Q);
    u16*   kbuf  = (u16*)(ws + OFF_K);
    u16*   vtbuf = (u16*)(ws + OFF_VT);
    u16*   patchA = (u16*)(ws + OFF_Q);   // reused before layer 0
    u16*   mlph   = (u16*)(ws + OFF_Q);   // reused inside MLP phase
    float* pooled = (float*)(ws + OFF_PL);
    u16*   hb16   = (u16*)(ws + OFF_HB);

    // ---- patch embedding ----
    im2col_kernel<<<(6272 * 768 + 255) / 256, 256, 0, stream>>>(imgs, patchA);
    cast_kernel<<<(589824 + 255) / 256, 256, 0, stream>>>(patch_w, wbuf, 589824);
    gemm_async<OM_PATCH, EPI_NONE, false><<<dim3(49, 6), 256, 0, stream>>>(
        patchA, wbuf, x, patch_b, nullptr, nullptr, 6272, 768, 768, 768, 768, 768);
    add_pos_kernel<<<(SROWS * DIM + 255) / 256, 256, 0, stream>>>(x, cls_tok, pos_emb);

    // ---- transformer layers ----
    for (int l = 0; l < LAYERS; ++l) {
        const long wstride = (long)DIM * DIM;
        ln_kernel<<<SROWS, 256, 0, stream>>>(x, ln1_g + l * DIM, ln1_b + l * DIM, h);

        // all 4 attention weights transposed in one dispatch: wbuf = [wq^T;wk^T;wv^T;wo^T]
        transpose_cast4<<<dim3(24, 24, 4), 256, 0, stream>>>(
            wq + l * wstride, wk + l * wstride, wv + l * wstride, wo + l * wstride, wbuf);

        // fused QKV: N=2304, scattered epilogue -> qbuf/kbuf/vtbuf
        gemm_async<OM_QKV, EPI_NONE, false><<<dim3(50, 18), 256, 0, stream>>>(
            h, wbuf, qbuf, bq + l * DIM, bk + l * DIM, bv + l * DIM,
            SROWS, 2304, DIM, DIM, DIM, 0);

        // fused attention: S, softmax, PV in one dispatch
        attn_fused<<<dim3(4, 384), 256, 0, stream>>>(qbuf, kbuf, vtbuf, obuf);

        // O projection + residual (B = wo^T slice)
        gemm_async<OM_F32, EPI_NONE, true><<<dim3(50, 6), 256, 0, stream>>>(
            obuf, wbuf + 3L * DIM * DIM, x, bo + l * DIM, nullptr, nullptr,
            SROWS, DIM, DIM, DIM, DIM, DIM);

        // MLP
        ln_kernel<<<SROWS, 256, 0, stream>>>(x, ln2_g + l * DIM, ln2_b + l * DIM, h);
        transpose_cast<<<dim3(96, 24), 256, 0, stream>>>(w1 + (long)l * DIM * MLPD, wbuf, DIM, MLPD);
        gemm_async<OM_BF16, EPI_GELU, false><<<dim3(50, 24), 256, 0, stream>>>(
            h, wbuf, mlph, b1 + l * MLPD, nullptr, nullptr,
            SROWS, MLPD, DIM, DIM, DIM, MLPD);
        transpose_cast<<<dim3(24, 96), 256, 0, stream>>>(w2 + (long)l * MLPD * DIM, wbuf, MLPD, DIM);
        gemm_async<OM_F32, EPI_NONE, true><<<dim3(50, 6), 256, 0, stream>>>(
            mlph, wbuf, x, b2 + l * DIM, nullptr, nullptr,
            SROWS, DIM, MLPD, MLPD, MLPD, DIM);
    }

    // ---- head ----
    mean_pool_kernel<<<(BATCH * DIM + 255) / 256, 256, 0, stream>>>(x, pooled);
    ln_kernel<<<BATCH, 256, 0, stream>>>(pooled, hn_g, hn_b, hb16);
    head_kernel<<<dim3(32, 4), 256, 0, stream>>>(hb16, hw, hbias, (float*)d_out);
}